// Round 1
// baseline (1129.552 us; speedup 1.0000x reference)
//
#include <hip/hip_runtime.h>
#include <math.h>

#define T_DIM 1000
#define C_DIM 500
#define U_DIM 100
#define S_DIM 201   // 2U+1
#define NEGINF (-INFINITY)

__device__ __forceinline__ float lse3f(float x1, float x2, float x3) {
    float m = fmaxf(fmaxf(x1, x2), x3);
    if (m == NEGINF) return NEGINF;
    float sum = __expf(x1 - m) + __expf(x2 - m) + __expf(x3 - m);
    return m + __logf(sum);
}

// Exact replica of reference _log_sub_exp (incl. the inf-substitution quirk).
__device__ __forceinline__ float log_sub_expf(float a, float b) {
    bool ia = isinf(a);
    bool ib = isinf(b);
    if (!ia && !ib) {
        float ans = b + __logf(__expf(a - b) - 1.0f);
        if (isinf(ans)) {
            // reference substitutes a2=-2000, b2=-2001:
            ans = -2001.0f + __logf(__expf(1.0f) - 1.0f);
        }
        return ans;
    }
    if (!ia && ib) return a;   // a finite, b = -inf
    return NEGINF;             // a = -inf
}

extern "C" __global__ void __launch_bounds__(256)
brctc_fwd(const float* __restrict__ nnet, const int* __restrict__ ys,
          const int* __restrict__ hlens, const int* __restrict__ ylens,
          float* __restrict__ a_l)
{
    const int b = blockIdx.x;
    const int s = threadIdx.x;
    __shared__ float sh_a[S_DIM];
    __shared__ int   sh_ys[U_DIM];

    if (s < U_DIM) sh_ys[s] = ys[b * U_DIM + s];
    __syncthreads();

    const int hl = hlens[b];
    const int yl = ylens[b];

    int  lab  = 0;
    bool skip = false;               // allow_skip[s]
    if (s < S_DIM) {
        if (s & 1) lab = sh_ys[(s - 1) >> 1];
        if ((s & 1) && s >= 3) skip = (sh_ys[(s - 1) >> 1] != sh_ys[(s - 3) >> 1]);
        sh_a[s] = (s == 0) ? 0.0f : NEGINF;   // a0
    }
    const bool valid = (s < S_DIM) && (s <= 2 * yl);
    const bool isodd = (s < S_DIM) && (s & 1);
    const int  l = (s - 1) >> 1;

    const float* __restrict__ base = nnet + (size_t)b * T_DIM * C_DIM;
    float*       __restrict__ alb  = a_l  + (size_t)b * T_DIM * U_DIM;

    __syncthreads();

    float p_cur = valid ? base[lab] : NEGINF;   // p_ext[t=0][s]
    for (int t = 0; t < T_DIM; ++t) {
        // prefetch next timestep's gathered prob (hides VMEM latency)
        float p_nxt = (valid && (t + 1 < T_DIM)) ? base[(size_t)(t + 1) * C_DIM + lab]
                                                 : NEGINF;
        float x1 = (s < S_DIM) ? sh_a[s] : NEGINF;
        float x2 = (s >= 1 && s < S_DIM) ? sh_a[s - 1] : NEGINF;
        float x3 = skip ? sh_a[s - 2] : NEGINF;
        float anew = p_cur + lse3f(x1, x2, x3);
        __syncthreads();
        if (s < S_DIM) sh_a[s] = anew;
        if (isodd) alb[t * U_DIM + l] = (t < hl) ? anew : NEGINF;  // masked a_l
        __syncthreads();
        p_cur = p_nxt;
    }
}

extern "C" __global__ void __launch_bounds__(256)
brctc_bwd(const float* __restrict__ nnet, const int* __restrict__ ys,
          const int* __restrict__ hlens, const int* __restrict__ ylens,
          const float* __restrict__ a_l, float* __restrict__ out)
{
    const int b = blockIdx.x;
    const int s = threadIdx.x;
    __shared__ float sh_b[S_DIM];
    __shared__ float sh_q[S_DIM];
    __shared__ float sh_lu[U_DIM];
    __shared__ int   sh_ys[U_DIM];

    if (s < U_DIM) sh_ys[s] = ys[b * U_DIM + s];
    __syncthreads();

    const int hl = hlens[b];
    const int yl = ylens[b];

    int  lab   = 0;
    bool skip2 = false;              // allow_skip_n2[s] = allow_skip[s+2]
    if (s < S_DIM) {
        if (s & 1) lab = sh_ys[(s - 1) >> 1];
        int s2 = s + 2;
        if (s2 < S_DIM && (s2 & 1) && s2 >= 3)
            skip2 = (sh_ys[(s2 - 1) >> 1] != sh_ys[(s2 - 3) >> 1]);
        sh_b[s] = NEGINF;            // initial beta carry
    }
    const bool valid = (s < S_DIM) && (s <= 2 * yl);
    const bool isodd = (s < S_DIM) && (s & 1);
    const int  l = (s - 1) >> 1;
    const float fin0 = (s == 2 * yl || s == 2 * yl - 1) ? 0.0f : NEGINF;  // beta_fin

    const float* __restrict__ base = nnet + (size_t)b * T_DIM * C_DIM;
    const float* __restrict__ alb  = a_l  + (size_t)b * T_DIM * U_DIM;

    float m_run   = NEGINF, acc = 0.0f;  // online LSE over t of loss_state
    float prev_bl = NEGINF;              // dead-masked b_l at t+1
    float p_hi    = NEGINF;              // p_ext[t+1][s]; t=T-1 -> -inf

    __syncthreads();

    for (int t = T_DIM - 1; t >= 0; --t) {
        // prefetch p_ext[t][s] (becomes p_hi next iteration) and alpha[t]
        float p_lo  = valid ? base[(size_t)t * C_DIM + lab] : NEGINF;
        float a_cur = isodd ? alb[t * U_DIM + l] : NEGINF;

        float q = (s < S_DIM) ? (p_hi + sh_b[s]) : NEGINF;
        if (s < S_DIM) sh_q[s] = q;
        __syncthreads();

        float q2 = (s + 1 < S_DIM) ? sh_q[s + 1] : NEGINF;
        float q3 = skip2 ? sh_q[s + 2] : NEGINF;
        float cand = lse3f(q, q2, q3);
        float bnew = (t == hl - 1) ? fin0 : cand;
        if (s < S_DIM) sh_b[s] = bnew;   // safe: sh_b only read pre-barrier

        if (isodd) {
            bool  dead = (a_cur == NEGINF);
            float bl_t = dead ? NEGINF : bnew;
            float bp = (t == T_DIM - 1) ? bl_t
                                        : log_sub_expf(bl_t, prev_bl + p_hi);
            float x = a_cur + bp - 0.1f * ((float)t / (float)hl);
            if (x != NEGINF) {
                if (x <= m_run) {
                    acc += __expf(x - m_run);
                } else {
                    acc = acc * __expf(m_run - x) + 1.0f;
                    m_run = x;
                }
            }
            prev_bl = bl_t;
        }
        __syncthreads();
        p_hi = p_lo;
    }

    if (isodd) sh_lu[l] = (m_run == NEGINF) ? NEGINF : (m_run + __logf(acc));
    __syncthreads();
    if (s == 0) {
        int cnt = 0;
        for (int u = 0; u < U_DIM; ++u) cnt += (sh_lu[u] != NEGINF) ? 1 : 0;
        int last = cnt - 1;
        if (last < 0) last = 0;
        if (last >= U_DIM) last = U_DIM - 1;
        out[b] = -sh_lu[last];
    }
}

extern "C" void kernel_launch(void* const* d_in, const int* in_sizes, int n_in,
                              void* d_out, int out_size, void* d_ws, size_t ws_size,
                              hipStream_t stream) {
    const float* nnet  = (const float*)d_in[0];
    const int*   ys    = (const int*)d_in[1];
    const int*   hlens = (const int*)d_in[2];
    const int*   ylens = (const int*)d_in[3];
    float*       outp  = (float*)d_out;
    float*       a_l   = (float*)d_ws;   // B*T*U floats = 12.8 MB scratch

    const int B = in_sizes[2];           // 32

    brctc_fwd<<<B, 256, 0, stream>>>(nnet, ys, hlens, ylens, a_l);
    brctc_bwd<<<B, 256, 0, stream>>>(nnet, ys, hlens, ylens, a_l, outp);
}